// Round 1
// baseline (701.163 us; speedup 1.0000x reference)
//
#include <hip/hip_runtime.h>

// HNM discriminative loss, MI355X — R4.
// predict (4,32,512,1024) f32, target (4,512,1024) i32 -> scalar f32.
// R4 theory: R3's 357us k_accum / ~315us k_var are ~90% device-scope f32
// atomic drain: 642K (resp. 39K) global atomicAdds land on ~40 (resp. 3)
// cache lines -> ~16K serialized same-line RMWs each at ~22ns (WRITE_SIZE
// 2528KB == atomic bytes exactly; VALUBusy 0.57%, HBM 4.9%).
// Fix: zero global atomics. Each block stores partials to a private slot
// (plain coalesced stores); k_reduce folds 1024x627 partials (2.6MB);
// k_var's per-block sq/pos slots reduced inside k_final. No memset needed.

#define K_CLS 19
#define C_CH 32
#define HW_SHIFT 19            // H*W = 512*1024 = 2^19
#define HW_SIZE (1 << HW_SHIFT)
#define CHUNK 2048             // pixels per block
#define NB 8                   // channel batches
#define BCH 4                  // channels per batch (NB*BCH == C_CH)
#define EPSF 1e-12f
#define THEA_F 0.5f
#define TWO_DELTA 3.0f
#define MIN_PIX 20.0f

// ws float layout (no atomics anywhere; every cell written before read)
#define NBLK 1024              // P / CHUNK for this problem size
#define PART_STRIDE 632        // 627 used, padded for alignment
#define OFF_PART 0                                  // [blk][PART_STRIDE]: 608 sums + 19 counts
#define OFF_RED  (NBLK * PART_STRIDE)               // 627 reduced: [ch*19+k], then 19 counts at +608
#define OFF_VPART (OFF_RED + 640)                   // [blk][64]: 19 sq + 19 pos
#define WS_FLOATS (OFF_VPART + NBLK * 64)

__device__ __forceinline__ void atomAddF(float* p, float v) {
  unsafeAtomicAdd(p, v);       // LDS-only now: ds_add_f32
}

// ---- Pass 1: per-class counts + feature sums -> private slot -------------
__global__ __launch_bounds__(256) void k_accum(
    const float* __restrict__ pred, const int* __restrict__ tgt,
    float* __restrict__ ws)
{
  __shared__ float s_sums[C_CH][4][20];   // replica per quarter-wave
  __shared__ float s_cnt[4][20];
  {
    float* z = &s_sums[0][0][0];
    for (int i = threadIdx.x; i < C_CH * 4 * 20; i += 256) z[i] = 0.f;
    if (threadIdx.x < 80) (&s_cnt[0][0])[threadIdx.x] = 0.f;
  }

  const int t = threadIdx.x;
  const int rep = (t >> 4) & 3;
  const size_t P0 = (size_t)blockIdx.x * CHUNK;   // 2048 | 2^19: never crosses image
  const int n_idx = (int)(P0 >> HW_SHIFT);
  const int hw0 = (int)(P0 & (HW_SIZE - 1));

  const int4 t0 = *reinterpret_cast<const int4*>(tgt + P0 + t * 4);
  const int4 t1 = *reinterpret_cast<const int4*>(tgt + P0 + 1024 + t * 4);
  int  sc[8] = {t0.x, t0.y, t0.z, t0.w, t1.x, t1.y, t1.z, t1.w};
  bool vl[8];
#pragma unroll
  for (int i = 0; i < 8; ++i) { vl[i] = (unsigned)sc[i] < K_CLS; if (!vl[i]) sc[i] = 0; }

  __syncthreads();

#pragma unroll
  for (int i = 0; i < 8; ++i) if (vl[i]) atomAddF(&s_cnt[rep][sc[i]], 1.f);

  const float* base = pred + (((size_t)n_idx * C_CH) << HW_SHIFT) + hw0;
#pragma unroll 1
  for (int b = 0; b < NB; ++b) {
    float4 r[2 * BCH];
#pragma unroll
    for (int j = 0; j < BCH; ++j) {
      const float* p = base + ((size_t)(b * BCH + j) << HW_SHIFT);
      r[2 * j]     = *reinterpret_cast<const float4*>(p + t * 4);
      r[2 * j + 1] = *reinterpret_cast<const float4*>(p + 1024 + t * 4);
    }
#pragma unroll
    for (int j = 0; j < BCH; ++j) {
      const int ch = b * BCH + j;
      const float x[8] = {r[2*j].x, r[2*j].y, r[2*j].z, r[2*j].w,
                          r[2*j+1].x, r[2*j+1].y, r[2*j+1].z, r[2*j+1].w};
#pragma unroll
      for (int i = 0; i < 8; ++i) if (vl[i]) atomAddF(&s_sums[ch][rep][sc[i]], x[i]);
    }
  }

  __syncthreads();
  // private slot: plain coalesced stores, no contention
  float* part = ws + OFF_PART + (size_t)blockIdx.x * PART_STRIDE;
  for (int i = t; i < C_CH * K_CLS; i += 256) {
    const int ch = i / K_CLS, k = i - ch * K_CLS;
    part[i] = s_sums[ch][0][k] + s_sums[ch][1][k] + s_sums[ch][2][k] + s_sums[ch][3][k];
  }
  if (t < K_CLS)
    part[C_CH * K_CLS + t] = s_cnt[0][t] + s_cnt[1][t] + s_cnt[2][t] + s_cnt[3][t];
}

// ---- Reduce 1024 partial slots -> 627 totals ------------------------------
__global__ __launch_bounds__(256) void k_reduce(float* __restrict__ ws, int nb)
{
  const int o = blockIdx.x;            // 0..626
  const int t = threadIdx.x;
  float a = 0.f;
  for (int b = t; b < nb; b += 256)
    a += ws[OFF_PART + (size_t)b * PART_STRIDE + o];
#pragma unroll
  for (int d = 32; d > 0; d >>= 1) a += __shfl_down(a, d, 64);
  __shared__ float s[4];
  if ((t & 63) == 0) s[t >> 6] = a;
  __syncthreads();
  if (t == 0) ws[OFF_RED + o] = s[0] + s[1] + s[2] + s[3];
}

// ---- Pass 2: per-pixel residuals (d^2 in registers) -> sq/pos slot --------
__global__ __launch_bounds__(256) void k_var(
    const float* __restrict__ pred, const int* __restrict__ tgt,
    float* __restrict__ ws)
{
  __shared__ float s_ctr[C_CH][K_CLS];
  __shared__ float s_sq[K_CLS];
  __shared__ float s_pos[K_CLS];
  for (int i = threadIdx.x; i < C_CH * K_CLS; i += 256) {
    const int k = i % K_CLS;
    (&s_ctr[0][0])[i] = ws[OFF_RED + i] / fmaxf(ws[OFF_RED + C_CH * K_CLS + k], 1.f);
  }
  if (threadIdx.x < K_CLS) { s_sq[threadIdx.x] = 0.f; s_pos[threadIdx.x] = 0.f; }

  const int t = threadIdx.x;
  const size_t P0 = (size_t)blockIdx.x * CHUNK;
  const int n_idx = (int)(P0 >> HW_SHIFT);
  const int hw0 = (int)(P0 & (HW_SIZE - 1));

  const int4 t0 = *reinterpret_cast<const int4*>(tgt + P0 + t * 4);
  const int4 t1 = *reinterpret_cast<const int4*>(tgt + P0 + 1024 + t * 4);
  int  sc[8] = {t0.x, t0.y, t0.z, t0.w, t1.x, t1.y, t1.z, t1.w};
  bool vl[8];
#pragma unroll
  for (int i = 0; i < 8; ++i) { vl[i] = (unsigned)sc[i] < K_CLS; if (!vl[i]) sc[i] = 0; }

  __syncthreads();

  float d2[8] = {0.f, 0.f, 0.f, 0.f, 0.f, 0.f, 0.f, 0.f};
  const float* base = pred + (((size_t)n_idx * C_CH) << HW_SHIFT) + hw0;
#pragma unroll 1
  for (int b = 0; b < NB; ++b) {
    float4 r[2 * BCH];
#pragma unroll
    for (int j = 0; j < BCH; ++j) {
      const float* p = base + ((size_t)(b * BCH + j) << HW_SHIFT);
      r[2 * j]     = *reinterpret_cast<const float4*>(p + t * 4);
      r[2 * j + 1] = *reinterpret_cast<const float4*>(p + 1024 + t * 4);
    }
#pragma unroll
    for (int j = 0; j < BCH; ++j) {
      const int ch = b * BCH + j;
      const float x[8] = {r[2*j].x, r[2*j].y, r[2*j].z, r[2*j].w,
                          r[2*j+1].x, r[2*j+1].y, r[2*j+1].z, r[2*j+1].w};
#pragma unroll
      for (int i = 0; i < 8; ++i) {
        const float c = s_ctr[ch][sc[i]];   // 19 consecutive words: ~4-way worst
        const float d = c - x[i];
        d2[i] = fmaf(d, d, d2[i]);
      }
    }
  }

#pragma unroll
  for (int i = 0; i < 8; ++i) {
    if (vl[i]) {
      const float r = sqrtf(d2[i] + EPSF) - THEA_F;
      if (r > 0.f) { atomAddF(&s_sq[sc[i]], r * r); atomAddF(&s_pos[sc[i]], 1.f); }
    }
  }

  __syncthreads();
  if (t < K_CLS) {
    float* vp = ws + OFF_VPART + (size_t)blockIdx.x * 64;
    vp[t]         = s_sq[t];
    vp[K_CLS + t] = s_pos[t];
  }
}

// ---- Finalize: reduce vparts, then loss_var + loss_dis + 0.001*loss_reg ---
__global__ __launch_bounds__(1024) void k_final(
    float* __restrict__ ws, float* __restrict__ out, int nb)
{
  __shared__ float s_ctr[C_CH * K_CLS];
  __shared__ float s_valid[K_CLS];
  __shared__ float s_sq[K_CLS];
  __shared__ float s_pos[K_CLS];
  __shared__ float s_red[3];
  __shared__ float s_ncls;
  const int t = threadIdx.x;
  if (t < 3) s_red[t] = 0.f;
  if (t < K_CLS) { s_sq[t] = 0.f; s_pos[t] = 0.f; }
  if (t < K_CLS) s_valid[t] = (ws[OFF_RED + C_CH * K_CLS + t] > MIN_PIX) ? 1.f : 0.f;
  for (int i = t; i < C_CH * K_CLS; i += 1024) {
    const int k = i % K_CLS;
    s_ctr[i] = ws[OFF_RED + i] / fmaxf(ws[OFF_RED + C_CH * K_CLS + k], 1.f);
  }
  __syncthreads();

  // reduce per-block sq/pos slots: 16 slices x 64 slots (38 live)
  {
    const int o = t & 63, slice = t >> 6;
    if (o < 2 * K_CLS) {
      float a = 0.f;
      for (int b = slice; b < nb; b += 16)
        a += ws[OFF_VPART + (size_t)b * 64 + o];
      atomAddF(o < K_CLS ? &s_sq[o] : &s_pos[o - K_CLS], a);
    }
  }
  __syncthreads();

  if (t == 0) {
    float n = 0.f;
    for (int k = 0; k < K_CLS; ++k) n += s_valid[k];
    s_ncls = fmaxf(n, 1.f);
  }
  if (t < K_CLS && s_valid[t] > 0.f) {
    atomAddF(&s_red[0], s_sq[t] / fmaxf(s_pos[t], 1.f));
    float nn = 0.f;
#pragma unroll
    for (int ch = 0; ch < C_CH; ++ch) {
      const float cv = s_ctr[ch * K_CLS + t];
      nn = fmaf(cv, cv, nn);
    }
    atomAddF(&s_red[2], sqrtf(nn + EPSF));
  }
  if (t < K_CLS * K_CLS) {
    const int a = t / K_CLS, b = t - (t / K_CLS) * K_CLS;
    if (a != b && s_valid[a] > 0.f && s_valid[b] > 0.f) {
      float dd = 0.f;
#pragma unroll
      for (int ch = 0; ch < C_CH; ++ch) {
        const float df = s_ctr[ch * K_CLS + a] - s_ctr[ch * K_CLS + b];
        dd = fmaf(df, df, dd);
      }
      const float dist = sqrtf(dd + EPSF);
      const float d = fmaxf(TWO_DELTA - dist, 0.f);
      if (d > 0.f) atomAddF(&s_red[1], d * d);
    }
  }
  __syncthreads();
  if (t == 0) {
    const float n = s_ncls;
    out[0] = s_red[0] / n
           + s_red[1] / fmaxf(n * (n - 1.f), 1.f)
           + 0.001f * s_red[2] / n;
  }
}

extern "C" void kernel_launch(void* const* d_in, const int* in_sizes, int n_in,
                              void* d_out, int out_size, void* d_ws, size_t ws_size,
                              hipStream_t stream) {
  const float* pred = (const float*)d_in[0];
  const int*   tgt  = (const int*)d_in[1];
  float* ws  = (float*)d_ws;
  float* out = (float*)d_out;
  const int P = in_sizes[1];            // n*h*w = 2097152
  const int nBlocks = P / CHUNK;        // 1024

  k_accum <<<nBlocks, 256, 0, stream>>>(pred, tgt, ws);
  k_reduce<<<C_CH * K_CLS + K_CLS, 256, 0, stream>>>(ws, nBlocks);
  k_var   <<<nBlocks, 256, 0, stream>>>(pred, tgt, ws);
  k_final <<<1, 1024, 0, stream>>>(ws, out, nBlocks);
}